// Round 5
// baseline (514.027 us; speedup 1.0000x reference)
//
#include <hip/hip_runtime.h>

#define NRUNS  128
#define TSTEPS 2048
#define NAG    16
#define SENS   7
#define HID    22
#define HP     24   // padded units per agent row in hpre
#define HPRE_BYTES ((size_t)NRUNS * TSTEPS * NAG * HP * 2)  // fp16

typedef float float2v __attribute__((ext_vector_type(2)));
typedef _Float16 half2v __attribute__((ext_vector_type(2)));

// DPP move, bound_ctrl=1 (invalid source lanes -> 0). All ctrls round-4-verified:
// 0x101 row_shl:1, 0x111 row_shr:1, 0x128 row_ror:8 (lane^8 within 16-row),
// 0xB1/0x4E/0x141 quad/half-mirror butterfly (round-1/3-verified, fallback path).
template<int CTRL>
__device__ __forceinline__ float dpp_mov(float v) {
    return __int_as_float(__builtin_amdgcn_update_dpp(
        0, __float_as_int(v), CTRL, 0xf, 0xf, true));
}

// Sum over {l, l^8, l^32} partners (bit4 is a redundant replica):
// round-4-verified. r[0]+r[1] == v[l] + v[l^32] under either swap convention.
__device__ __forceinline__ float grp_sum_r(float v) {
    v += dpp_mov<0x128>(v);
    unsigned u = __float_as_uint(v);
    auto r = __builtin_amdgcn_permlane32_swap(u, u, false, false);
    return __uint_as_float(r[0]) + __uint_as_float(r[1]);
}

// ============================= PASS 1 =====================================
// hpre[run][t][agent][24] (fp16) = b1 + W1x . x   (x-part of hidden pre-act)
__global__ void __launch_bounds__(256) hpre_kernel(
    const float* __restrict__ runs, const float* __restrict__ W1,
    const float* __restrict__ b1, _Float16* __restrict__ hpre)
{
    const int tid = blockIdx.x * 256 + threadIdx.x;   // 524288 threads
    const int s8  = tid & 7;                          // unit slice (3 units)
    const int rb  = tid >> 3;                         // 0..65535
    float w[3][SENS], bb[3];
#pragma unroll
    for (int u = 0; u < 3; ++u) {
        int j = s8 * 3 + u; bool valid = j < HID; int jj = valid ? j : 0;
        float m = valid ? 1.f : 0.f;
#pragma unroll
        for (int k = 0; k < SENS; ++k) w[u][k] = m * W1[jj * 9 + k];
        bb[u] = m * b1[jj];
    }
#pragma unroll 1
    for (int q = 0; q < 64; ++q) {                    // 4,194,304 rows total
        long r = (long)rb + (long)q * 65536;
        const float* x = runs + r * SENS;
        float x0=x[0],x1=x[1],x2=x[2],x3=x[3],x4=x[4],x5=x[5],x6=x[6];
        _Float16* hw = hpre + r * HP + s8 * 3;
#pragma unroll
        for (int u = 0; u < 3; ++u) {
            float a = bb[u];
            a = fmaf(w[u][0], x0, a); a = fmaf(w[u][1], x1, a);
            a = fmaf(w[u][2], x2, a); a = fmaf(w[u][3], x3, a);
            a = fmaf(w[u][4], x4, a); a = fmaf(w[u][5], x5, a);
            a = fmaf(w[u][6], x6, a);
            hw[u] = (_Float16)a;
        }
    }
}

// ============================= PASS 2 =====================================
// Serial systolic wave: lane = [bit5 bit4 bit3]*8 + g. g = agent group (0..7),
// sub2 = bits(3,5) -> 4 slices x 6 units; bit4 = redundant replica (r4-verified).
struct HBlk { half2v h[2][6]; };   // 2 pairs x (3 even + 3 odd dwords)

__global__ void __launch_bounds__(64, 1) comm_net_kernel(
    const half2v* __restrict__ hpre2,     // d_ws as fp16 pairs
    const float* __restrict__ W1,
    const float* __restrict__ W2,
    const float* __restrict__ b2,
    const float* __restrict__ comm_init,
    float* __restrict__ out)
{
    const int run  = blockIdx.x;
    const int lane = threadIdx.x & 63;
    const int g    = lane & 7;
    const int sub2 = ((lane >> 3) & 1) | ((lane >> 4) & 2);
    const bool g0  = (g == 0);
    const bool g7  = (g == 7);

    // per-lane weights for units j = sub2*6 .. +5 (no W1 x-rows, no b1!)
    float wA[6], wAm[6], wB[6], wBm[6], w20[6], w21[6];
#pragma unroll
    for (int v = 0; v < 6; ++v) {
        int j = sub2 * 6 + v; bool valid = j < HID; int jj = valid ? j : 0;
        float m = valid ? 1.f : 0.f;
        float wa = m * W1[jj * 9 + 7];   // weight on comm[i]
        float wb = m * W1[jj * 9 + 8];   // weight on comm[i+2]
        wA[v] = wa; wAm[v] = g0 ? 0.f : wa;
        wB[v] = wb; wBm[v] = g7 ? 0.f : wb;
        w20[v] = m * W2[jj];
        w21[v] = m * W2[HID + jj];
    }
    // fold biases pre-reduce: exactly one lane per bit4-half (sub2==0) adds them
    const float b20s = (sub2 == 0) ? b2[0] : 0.f;
    const float b21s = (sub2 == 0) ? b2[1] : 0.f;

    const float* ci = comm_init + run * (NAG + 2);
    float prevV = ci[2 * g + 2];
    const float initV_e = ci[2 * g + 1];
    const float initV_o = ci[2 * g + 2];

    const half2v* hp2 = hpre2 + (long)run * (TSTEPS * NAG * HP / 2);
    float*        po  = out   + (size_t)run * TSTEPS * NAG;

    auto substep_even = [&](const float (&h)[6], float& o0out) {
        float cL = dpp_mov<0x111>(prevV);            // from g-1 (masked at g=0)
        float a[6];
#pragma unroll
        for (int v = 0; v < 6; ++v)
            a[v] = fmaxf(fmaf(wAm[v], cL, fmaf(wB[v], prevV, h[v])), 0.f);
        float q0a = fmaf(w20[1], a[1], fmaf(w20[0], a[0], b20s));
        float q0b = fmaf(w20[3], a[3], w20[2] * a[2]);
        float q0c = fmaf(w20[5], a[5], w20[4] * a[4]);
        float q1a = fmaf(w21[1], a[1], fmaf(w21[0], a[0], b21s));
        float q1b = fmaf(w21[3], a[3], w21[2] * a[2]);
        float q1c = fmaf(w21[5], a[5], w21[4] * a[4]);
        prevV = grp_sum_r((q1a + q1b) + q1c);        // comm[2g+1]
        o0out = grp_sum_r((q0a + q0b) + q0c);
    };
    auto substep_odd = [&](const float (&h)[6], float& o0out) {
        float cR = dpp_mov<0x101>(prevV);            // from g+1 (masked at g=7)
        float a[6];
#pragma unroll
        for (int v = 0; v < 6; ++v)
            a[v] = fmaxf(fmaf(wBm[v], cR, fmaf(wA[v], prevV, h[v])), 0.f);
        float q0a = fmaf(w20[1], a[1], fmaf(w20[0], a[0], b20s));
        float q0b = fmaf(w20[3], a[3], w20[2] * a[2]);
        float q0c = fmaf(w20[5], a[5], w20[4] * a[4]);
        float q1a = fmaf(w21[1], a[1], fmaf(w21[0], a[0], b21s));
        float q1b = fmaf(w21[3], a[3], w21[2] * a[2]);
        float q1c = fmaf(w21[5], a[5], w21[4] * a[4]);
        prevV = grp_sum_r((q1a + q1b) + q1c);        // comm[2g+2]
        o0out = grp_sum_r((q0a + q0b) + q0c);
    };

    // guarded pair for pipeline ramp in/out
    auto ramp_pair = [&](int s) {
        int t  = (s >> 1) - g;
        int tc = t < 0 ? 0 : (t > TSTEPS - 1 ? TSTEPS - 1 : t);
        long db = (long)tc * 192 + (2 * g) * 12 + sub2 * 3;  // dword index
        float he[6], ho[6];
#pragma unroll
        for (int k = 0; k < 3; ++k) {
            half2v e = hp2[db + k], o = hp2[db + 12 + k];
            he[2*k] = (float)e.x; he[2*k+1] = (float)e.y;
            ho[2*k] = (float)o.x; ho[2*k+1] = (float)o.y;
        }
        bool inr = (t >= 0) && (t < TSTEPS);
        float o0;
        substep_even(he, o0);
        if (inr) po[(size_t)t * NAG + 2 * g] = o0;
        prevV = (t < 0) ? initV_e : prevV;
        substep_odd(ho, o0);
        if (inr) po[(size_t)t * NAG + 2 * g + 1] = o0;
        prevV = (t < 0) ? initV_o : prevV;
    };

    // ---- ramp-in: s = 0..15 (8 pairs) ----
#pragma unroll 1
    for (int s = 0; s <= 14; s += 2) ramp_pair(s);

    // ---- steady: 2040 pairs = 1020 blocks of 2; t = pair + 8 - g ----
    const long db0 = ((long)(8 - g) * NAG + 2 * g) * 12 + sub2 * 3;
    float* oe = po + (size_t)(8 - g) * NAG + 2 * g;

    auto load_blk = [&](HBlk& H, long db) {
#pragma unroll
        for (int j = 0; j < 2; ++j)
#pragma unroll
            for (int k = 0; k < 3; ++k) {
                H.h[j][k]     = hp2[db + j * 192 + k];
                H.h[j][3 + k] = hp2[db + j * 192 + 12 + k];
            }
    };
    auto process_blk = [&](const HBlk& H) {
#pragma unroll
        for (int j = 0; j < 2; ++j) {
            float he[6], ho[6];
#pragma unroll
            for (int k = 0; k < 3; ++k) {
                he[2*k] = (float)H.h[j][k].x;     he[2*k+1] = (float)H.h[j][k].y;
                ho[2*k] = (float)H.h[j][3+k].x;   ho[2*k+1] = (float)H.h[j][3+k].y;
            }
            float o0;
            substep_even(he, o0); oe[0] = o0;
            substep_odd (ho, o0); oe[1] = o0;
            oe += NAG;
        }
    };

    HBlk HA, HB, HC, HD;                 // depth-4 pipeline (~1200 cyc cover)
    load_blk(HA, db0);
    load_blk(HB, db0 + 384);
    load_blk(HC, db0 + 768);
    load_blk(HD, db0 + 1152);
#pragma unroll 1
    for (int bm = 0; bm < 1016; bm += 4) {
        process_blk(HA); load_blk(HA, db0 + (long)(bm + 4) * 384);
        process_blk(HB); load_blk(HB, db0 + (long)(bm + 5) * 384);
        process_blk(HC); load_blk(HC, db0 + (long)(bm + 6) * 384);
        process_blk(HD); load_blk(HD, db0 + (long)(bm + 7) * 384);
    }
    process_blk(HA); process_blk(HB); process_blk(HC); process_blk(HD);

    // ---- ramp-out: 7 guarded pairs ----
#pragma unroll 1
    for (int s = 2 * TSTEPS; s <= 2 * TSTEPS + 12; s += 2) ramp_pair(s);
}

// ===================== FALLBACK (round-3 verified, if ws too small) ========
__device__ __forceinline__ float grp_reduce_fb(float v) {
    v += dpp_mov<0xB1>(v);
    v += dpp_mov<0x4E>(v);
    v += dpp_mov<0x141>(v);
    return v;
}
__device__ __forceinline__ float bperm_fb(int byteaddr, float v) {
    return __int_as_float(__builtin_amdgcn_ds_bpermute(byteaddr, __float_as_int(v)));
}
struct RawBlk { float2v v[4][7]; };
struct XpBlk  { float e[4][3]; float o[4][3]; };

__global__ void __launch_bounds__(64, 1) comm_net_fb(
    const float* __restrict__ runs, const float* __restrict__ comm_init,
    const float* __restrict__ W1, const float* __restrict__ b1,
    const float* __restrict__ W2, const float* __restrict__ b2,
    float* __restrict__ out)
{
    const int run  = blockIdx.x;
    const int lane = threadIdx.x & 63;
    const int g    = lane >> 3;
    const int sub  = lane & 7;
    const bool g0  = (g == 0);
    const bool g7  = (g == 7);
    float w1x[3][SENS], wA[3], wB[3], b1v[3], w20[3], w21[3];
#pragma unroll
    for (int u = 0; u < 3; ++u) {
        int j = sub * 3 + u; bool valid = (j < HID); int jj = valid ? j : 0;
        float m = valid ? 1.0f : 0.0f;
#pragma unroll
        for (int k = 0; k < SENS; ++k) w1x[u][k] = m * W1[jj * 9 + k];
        wA[u] = m * W1[jj * 9 + 7]; wB[u] = m * W1[jj * 9 + 8];
        b1v[u] = m * b1[jj]; w20[u] = m * W2[jj]; w21[u] = m * W2[HID + jj];
    }
    const float b20 = b2[0], b21 = b2[1];
    const int addr_even = ((lane - 8) & 63) * 4;
    const int addr_odd  = ((lane + 8) & 63) * 4;
    const float* ci = comm_init + run * (NAG + 2);
    float prevV = ci[2 * g + 2];
    const float initV_e = ci[2 * g + 1];
    const float initV_o = ci[2 * g + 2];
    const float* pr = runs + (size_t)run * TSTEPS * NAG * SENS;
    float*       po = out  + (size_t)run * TSTEPS * NAG;
    auto xpart_pair = [&](const float2v (&r)[7], float (&ae)[3], float (&ao)[3]) {
#pragma unroll
        for (int u = 0; u < 3; ++u) {
            float e = b1v[u];
            e = fmaf(w1x[u][0], r[0].x, e); e = fmaf(w1x[u][1], r[0].y, e);
            e = fmaf(w1x[u][2], r[1].x, e); e = fmaf(w1x[u][3], r[1].y, e);
            e = fmaf(w1x[u][4], r[2].x, e); e = fmaf(w1x[u][5], r[2].y, e);
            e = fmaf(w1x[u][6], r[3].x, e);
            ae[u] = e;
            float o = b1v[u];
            o = fmaf(w1x[u][0], r[3].y, o); o = fmaf(w1x[u][1], r[4].x, o);
            o = fmaf(w1x[u][2], r[4].y, o); o = fmaf(w1x[u][3], r[5].x, o);
            o = fmaf(w1x[u][4], r[5].y, o); o = fmaf(w1x[u][5], r[6].x, o);
            o = fmaf(w1x[u][6], r[6].y, o);
            ao[u] = o;
        }
    };
    auto substep_even = [&](float x0, float x1, float x2, float& o0out) {
        float cross = bperm_fb(addr_even, prevV);
        float cL = g0 ? 0.f : cross;
        float a0 = fmaxf(fmaf(wA[0], cL, fmaf(wB[0], prevV, x0)), 0.f);
        float a1 = fmaxf(fmaf(wA[1], cL, fmaf(wB[1], prevV, x1)), 0.f);
        float a2 = fmaxf(fmaf(wA[2], cL, fmaf(wB[2], prevV, x2)), 0.f);
        float p0 = w20[0]*a0; p0 = fmaf(w20[1],a1,p0); p0 = fmaf(w20[2],a2,p0);
        float p1 = w21[0]*a0; p1 = fmaf(w21[1],a1,p1); p1 = fmaf(w21[2],a2,p1);
        o0out = grp_reduce_fb(p0) + b20;
        prevV = grp_reduce_fb(p1) + b21;
    };
    auto substep_odd = [&](float x0, float x1, float x2, float& o0out) {
        float cross = bperm_fb(addr_odd, prevV);
        float cR = g7 ? 0.f : cross;
        float a0 = fmaxf(fmaf(wB[0], cR, fmaf(wA[0], prevV, x0)), 0.f);
        float a1 = fmaxf(fmaf(wB[1], cR, fmaf(wA[1], prevV, x1)), 0.f);
        float a2 = fmaxf(fmaf(wB[2], cR, fmaf(wA[2], prevV, x2)), 0.f);
        float p0 = w20[0]*a0; p0 = fmaf(w20[1],a1,p0); p0 = fmaf(w20[2],a2,p0);
        float p1 = w21[0]*a0; p1 = fmaf(w21[1],a1,p1); p1 = fmaf(w21[2],a2,p1);
        o0out = grp_reduce_fb(p0) + b20;
        prevV = grp_reduce_fb(p1) + b21;
    };
    auto ramp_pair = [&](int s) {
        int t  = (s >> 1) - g;
        int tc = t < 0 ? 0 : (t > TSTEPS - 1 ? TSTEPS - 1 : t);
        const float2v* xp = (const float2v*)(pr + ((size_t)tc * NAG + 2 * g) * SENS);
        float2v r[7];
#pragma unroll
        for (int k = 0; k < 7; ++k) r[k] = xp[k];
        float ae[3], ao[3];
        xpart_pair(r, ae, ao);
        bool inr = (t >= 0) && (t < TSTEPS);
        float o0;
        substep_even(ae[0], ae[1], ae[2], o0);
        if (inr) po[(size_t)t * NAG + 2 * g] = o0;
        prevV = (t < 0) ? initV_e : prevV;
        substep_odd(ao[0], ao[1], ao[2], o0);
        if (inr) po[(size_t)t * NAG + 2 * g + 1] = o0;
        prevV = (t < 0) ? initV_o : prevV;
    };
#pragma unroll 1
    for (int s = 0; s <= 14; s += 2) ramp_pair(s);
    const float2v* xv = (const float2v*)(pr + ((size_t)(8 - g) * NAG + 2 * g) * SENS);
    float* oe = po + (size_t)(8 - g) * NAG + 2 * g;
    RawBlk RA, RB; XpBlk P0, P1;
    auto load_blk = [&](RawBlk& R, const float2v* p) {
#pragma unroll
        for (int j = 0; j < 4; ++j)
#pragma unroll
            for (int k = 0; k < 7; ++k) R.v[j][k] = p[j * 56 + k];
    };
    auto xpart_blk = [&](XpBlk& P, const RawBlk& R) {
#pragma unroll
        for (int j = 0; j < 4; ++j) xpart_pair(R.v[j], P.e[j], P.o[j]);
    };
    auto process_blk = [&](const XpBlk& P) {
#pragma unroll
        for (int j = 0; j < 4; ++j) {
            float o0;
            substep_even(P.e[j][0], P.e[j][1], P.e[j][2], o0); oe[0] = o0;
            substep_odd (P.o[j][0], P.o[j][1], P.o[j][2], o0); oe[1] = o0;
            oe += NAG;
        }
    };
    load_blk(RA, xv); load_blk(RB, xv + 224);
    xpart_blk(P0, RA); load_blk(RA, xv + 2 * 224);
#pragma unroll 1
    for (int bm = 0; bm < 506; bm += 2) {
        xpart_blk(P1, RB); load_blk(RB, xv + (size_t)(bm + 3) * 224);
        process_blk(P0);
        xpart_blk(P0, RA); load_blk(RA, xv + (size_t)(bm + 4) * 224);
        process_blk(P1);
    }
    xpart_blk(P1, RB); load_blk(RB, xv + (size_t)509 * 224);
    process_blk(P0);
    xpart_blk(P0, RA); process_blk(P1);
    xpart_blk(P1, RB); process_blk(P0); process_blk(P1);
#pragma unroll 1
    for (int s = 2 * TSTEPS; s <= 2 * TSTEPS + 12; s += 2) ramp_pair(s);
}

extern "C" void kernel_launch(void* const* d_in, const int* in_sizes, int n_in,
                              void* d_out, int out_size, void* d_ws, size_t ws_size,
                              hipStream_t stream) {
    const float* runs      = (const float*)d_in[0];
    const float* comm_init = (const float*)d_in[1];
    const float* W1        = (const float*)d_in[2];
    const float* b1        = (const float*)d_in[3];
    const float* W2        = (const float*)d_in[4];
    const float* b2        = (const float*)d_in[5];
    float* out = (float*)d_out;

    if (ws_size >= HPRE_BYTES) {
        _Float16* hpre = (_Float16*)d_ws;
        hipLaunchKernelGGL(hpre_kernel, dim3(2048), dim3(256), 0, stream,
                           runs, W1, b1, hpre);
        hipLaunchKernelGGL(comm_net_kernel, dim3(NRUNS), dim3(64), 0, stream,
                           (const half2v*)hpre, W1, W2, b2, comm_init, out);
    } else {
        hipLaunchKernelGGL(comm_net_fb, dim3(NRUNS), dim3(64), 0, stream,
                           runs, comm_init, W1, b1, W2, b2, out);
    }
}

// Round 6
// 472.311 us; speedup vs baseline: 1.0883x; 1.0883x over previous
//
#include <hip/hip_runtime.h>

#define NRUNS  128
#define TSTEPS 2048
#define NAG    16
#define SENS   7
#define HID    22
#define HP     24   // padded units per agent row in hpre (48 B/row as f16)
#define NROWS  ((long)NRUNS * TSTEPS * NAG)           // 4,194,304 agent-rows
#define HPRE_BYTES ((size_t)NROWS * HP * 2)           // 201 MB fp16

typedef float float2v __attribute__((ext_vector_type(2)));
typedef _Float16 half2v __attribute__((ext_vector_type(2)));
typedef unsigned int uint3v __attribute__((ext_vector_type(3)));

// DPP move, bound_ctrl=1 (invalid source lanes -> 0). Verified on HW (r4/r5):
// 0x101 row_shl:1, 0x111 row_shr:1, 0x128 row_ror:8 (lane^8 within 16-row).
// 0xB1/0x4E/0x141: butterfly ctrls (r1/r3-verified, fallback path).
template<int CTRL>
__device__ __forceinline__ float dpp_mov(float v) {
    return __int_as_float(__builtin_amdgcn_update_dpp(
        0, __float_as_int(v), CTRL, 0xf, 0xf, true));
}

// Sum over {l, l^8, l^32} (bit4 = redundant replica). Verified r4/r5.
__device__ __forceinline__ float grp_sum_r(float v) {
    v += dpp_mov<0x128>(v);
    unsigned u = __float_as_uint(v);
    auto r = __builtin_amdgcn_permlane32_swap(u, u, false, false);
    return __uint_as_float(r[0]) + __uint_as_float(r[1]);
}

// ============================= PASS 1 =====================================
// hpre[row][24] (fp16) = b1 + W1x . x ; 4 threads per row (6 units each).
__global__ void __launch_bounds__(256) hpre_kernel(
    const float* __restrict__ runs, const float* __restrict__ W1,
    const float* __restrict__ b1, char* __restrict__ hpre)
{
    const int tid = blockIdx.x * 256 + threadIdx.x;   // 1,048,576 threads
    const int q   = tid & 3;                          // row quarter: units q*6..+5
    const int rr  = tid >> 2;                         // 0..262143
    float w[6][SENS], bb[6];
#pragma unroll
    for (int u = 0; u < 6; ++u) {
        int j = q * 6 + u; bool valid = j < HID; int jj = valid ? j : 0;
        float m = valid ? 1.f : 0.f;
#pragma unroll
        for (int k = 0; k < SENS; ++k) w[u][k] = m * W1[jj * 9 + k];
        bb[u] = m * b1[jj];
    }
#pragma unroll 1
    for (int it = 0; it < 16; ++it) {
        long r = (long)rr + (long)it * 262144;
        const float* x = runs + r * SENS;
        float x0=x[0],x1=x[1],x2=x[2],x3=x[3],x4=x[4],x5=x[5],x6=x[6];
        float h[6];
#pragma unroll
        for (int u = 0; u < 6; ++u) {
            float a = bb[u];
            a = fmaf(w[u][0], x0, a); a = fmaf(w[u][1], x1, a);
            a = fmaf(w[u][2], x2, a); a = fmaf(w[u][3], x3, a);
            a = fmaf(w[u][4], x4, a); a = fmaf(w[u][5], x5, a);
            a = fmaf(w[u][6], x6, a);
            h[u] = a;
        }
        uint3v wv;
#pragma unroll
        for (int k = 0; k < 3; ++k) {
            half2v p; p.x = (_Float16)h[2*k]; p.y = (_Float16)h[2*k+1];
            wv[k] = __builtin_bit_cast(unsigned int, p);
        }
        *(uint3v*)(hpre + r * 48 + q * 12) = wv;
    }
}

// ============================= PASS 2 =====================================
// Serial systolic wave. lane: g = bits0-2 (agent group), sub2 = bits(3,5)
// (4 slices x 6 units), bit4 = redundant replica. Verified mapping (r4/r5).
struct HBlk { unsigned int e[2][3], o[2][3]; };   // 2 pairs x (3+3 dwords)

__global__ void __launch_bounds__(64, 1) comm_net_kernel(
    const unsigned int* __restrict__ hpu,  // hpre as dwords
    char* __restrict__ scratch,            // == hpre; q0 partials overwrite
    const float* __restrict__ W1,
    const float* __restrict__ W2,
    const float* __restrict__ b2,
    const float* __restrict__ comm_init)
{
    const int run  = blockIdx.x;
    const int lane = threadIdx.x & 63;
    const int g    = lane & 7;
    const int sub2 = ((lane >> 3) & 1) | ((lane >> 4) & 2);
    const int s4   = (lane >> 3) * 4;      // partial-store byte slot
    const bool g0  = (g == 0);
    const bool g7  = (g == 7);

    float wA[6], wAm[6], wB[6], wBm[6], w20[6], w21[6];
#pragma unroll
    for (int v = 0; v < 6; ++v) {
        int j = sub2 * 6 + v; bool valid = j < HID; int jj = valid ? j : 0;
        float m = valid ? 1.f : 0.f;
        float wa = m * W1[jj * 9 + 7];
        float wb = m * W1[jj * 9 + 8];
        wA[v] = wa; wAm[v] = g0 ? 0.f : wa;
        wB[v] = wb; wBm[v] = g7 ? 0.f : wb;
        w20[v] = m * W2[jj];
        w21[v] = m * W2[HID + jj];
    }
    const float b21s = (sub2 == 0) ? b2[1] : 0.f;  // pre-reduce fold (r5-verified)

    const float* ci = comm_init + run * (NAG + 2);
    float prevV = ci[2 * g + 2];
    const float initV_e = ci[2 * g + 1];
    const float initV_o = ci[2 * g + 2];

    const unsigned int* hp = hpu + (long)run * (TSTEPS * NAG * 12);
    char* scr = scratch + (long)run * (TSTEPS * NAG * 48);

    // even sub-step: agent 2g; cross cL from g-1 (row_shr:1, masked at g0).
    // Returns per-lane q0 partial (control), updates prevV (comm chain).
    auto sub_e = [&](const unsigned int (&hd)[3]) -> float {
        float cL = dpp_mov<0x111>(prevV);
        float a[6];
#pragma unroll
        for (int k = 0; k < 3; ++k) {
            half2v h2 = __builtin_bit_cast(half2v, hd[k]);
            a[2*k]   = fmaxf(fmaf(wAm[2*k],   cL, fmaf(wB[2*k],   prevV, (float)h2.x)), 0.f);
            a[2*k+1] = fmaxf(fmaf(wAm[2*k+1], cL, fmaf(wB[2*k+1], prevV, (float)h2.y)), 0.f);
        }
        float q1x = fmaf(w21[0],a[0], fmaf(w21[2],a[2], fmaf(w21[4],a[4], b21s)));
        float q1y = fmaf(w21[1],a[1], fmaf(w21[3],a[3], w21[5]*a[5]));
        prevV = grp_sum_r(q1x + q1y);          // comm[2g+1]
        float q0x = fmaf(w20[0],a[0], fmaf(w20[2],a[2], w20[4]*a[4]));
        float q0y = fmaf(w20[1],a[1], fmaf(w20[3],a[3], w20[5]*a[5]));
        return q0x + q0y;
    };
    // odd sub-step: agent 2g+1; cross cR from g+1 (row_shl:1, masked at g7).
    auto sub_o = [&](const unsigned int (&hd)[3]) -> float {
        float cR = dpp_mov<0x101>(prevV);
        float a[6];
#pragma unroll
        for (int k = 0; k < 3; ++k) {
            half2v h2 = __builtin_bit_cast(half2v, hd[k]);
            a[2*k]   = fmaxf(fmaf(wBm[2*k],   cR, fmaf(wA[2*k],   prevV, (float)h2.x)), 0.f);
            a[2*k+1] = fmaxf(fmaf(wBm[2*k+1], cR, fmaf(wA[2*k+1], prevV, (float)h2.y)), 0.f);
        }
        float q1x = fmaf(w21[0],a[0], fmaf(w21[2],a[2], fmaf(w21[4],a[4], b21s)));
        float q1y = fmaf(w21[1],a[1], fmaf(w21[3],a[3], w21[5]*a[5]));
        prevV = grp_sum_r(q1x + q1y);          // comm[2g+2]
        float q0x = fmaf(w20[0],a[0], fmaf(w20[2],a[2], w20[4]*a[4]));
        float q0y = fmaf(w20[1],a[1], fmaf(w20[3],a[3], w20[5]*a[5]));
        return q0x + q0y;
    };

    // guarded pair for pipeline ramp in/out (15 total)
    auto ramp_pair = [&](int s) {
        int t  = (s >> 1) - g;
        int tc = t < 0 ? 0 : (t > TSTEPS - 1 ? TSTEPS - 1 : t);
        long db = (long)tc * 192 + (2 * g) * 12 + sub2 * 3;
        unsigned int he[3], ho[3];
#pragma unroll
        for (int k = 0; k < 3; ++k) { he[k] = hp[db + k]; ho[k] = hp[db + 12 + k]; }
        bool inr = (t >= 0) && (t < TSTEPS);
        float q0 = sub_e(he);
        if (inr) *(float*)(scr + (long)(t * NAG + 2 * g) * 48 + s4) = q0;
        prevV = (t < 0) ? initV_e : prevV;
        q0 = sub_o(ho);
        if (inr) *(float*)(scr + (long)(t * NAG + 2 * g + 1) * 48 + s4) = q0;
        prevV = (t < 0) ? initV_o : prevV;
    };

    // ---- ramp-in: s = 0..15 (8 pairs) ----
#pragma unroll 1
    for (int s = 0; s <= 14; s += 2) ramp_pair(s);

    // ---- steady: 2040 pairs = 1020 blocks of 2; t = pair + 8 - g ----
    const long db0 = ((long)(8 - g) * NAG + 2 * g) * 12 + sub2 * 3;
    char* qp = scr + (long)((8 - g) * NAG + 2 * g) * 48 + s4;

    auto load_blk = [&](HBlk& H, long db) {
#pragma unroll
        for (int j = 0; j < 2; ++j)
#pragma unroll
            for (int k = 0; k < 3; ++k) {
                H.e[j][k] = hp[db + j * 192 + k];
                H.o[j][k] = hp[db + j * 192 + 12 + k];
            }
    };
    auto process_blk = [&](const HBlk& H) {
#pragma unroll
        for (int j = 0; j < 2; ++j) {
            float q0 = sub_e(H.e[j]);
            *(float*)qp = q0;                    // row (t, 2g) partial
            q0 = sub_o(H.o[j]);
            *(float*)(qp + 48) = q0;             // row (t, 2g+1) partial
            qp += 16 * 48;
        }
    };

    HBlk HA, HB, HC, HD;                 // depth-4 (8-pair) prefetch pipeline
    load_blk(HA, db0);
    load_blk(HB, db0 + 384);
    load_blk(HC, db0 + 768);
    load_blk(HD, db0 + 1152);
#pragma unroll 1
    for (int bm = 0; bm < 1016; bm += 4) {
        process_blk(HA); load_blk(HA, db0 + (long)(bm + 4) * 384);
        process_blk(HB); load_blk(HB, db0 + (long)(bm + 5) * 384);
        process_blk(HC); load_blk(HC, db0 + (long)(bm + 6) * 384);
        process_blk(HD); load_blk(HD, db0 + (long)(bm + 7) * 384);
    }
    process_blk(HA); process_blk(HB); process_blk(HC); process_blk(HD);

    // ---- ramp-out: 7 guarded pairs ----
#pragma unroll 1
    for (int s = 2 * TSTEPS; s <= 2 * TSTEPS + 12; s += 2) ramp_pair(s);
}

// ============================= PASS 3 =====================================
// out[row] = b20 + sum of the 4 distinct slice partials (s = 0,1,4,5).
__global__ void __launch_bounds__(256) finalize_kernel(
    const char* __restrict__ scratch, const float* __restrict__ b2,
    float* __restrict__ out)
{
    long r = (long)blockIdx.x * 256 + threadIdx.x;   // 4,194,304 rows
    const float* p = (const float*)(scratch + r * 48);
    float2v ab = *(const float2v*)p;         // s=0,1
    float2v cd = *(const float2v*)(p + 4);   // s=4,5
    out[r] = b2[0] + ((ab.x + ab.y) + (cd.x + cd.y));
}

// ===================== FALLBACK (round-3 verified, if ws too small) ========
__device__ __forceinline__ float grp_reduce_fb(float v) {
    v += dpp_mov<0xB1>(v);
    v += dpp_mov<0x4E>(v);
    v += dpp_mov<0x141>(v);
    return v;
}
__device__ __forceinline__ float bperm_fb(int byteaddr, float v) {
    return __int_as_float(__builtin_amdgcn_ds_bpermute(byteaddr, __float_as_int(v)));
}
struct RawBlk { float2v v[4][7]; };
struct XpBlk  { float e[4][3]; float o[4][3]; };

__global__ void __launch_bounds__(64, 1) comm_net_fb(
    const float* __restrict__ runs, const float* __restrict__ comm_init,
    const float* __restrict__ W1, const float* __restrict__ b1,
    const float* __restrict__ W2, const float* __restrict__ b2,
    float* __restrict__ out)
{
    const int run  = blockIdx.x;
    const int lane = threadIdx.x & 63;
    const int g    = lane >> 3;
    const int sub  = lane & 7;
    const bool g0  = (g == 0);
    const bool g7  = (g == 7);
    float w1x[3][SENS], wA[3], wB[3], b1v[3], w20[3], w21[3];
#pragma unroll
    for (int u = 0; u < 3; ++u) {
        int j = sub * 3 + u; bool valid = (j < HID); int jj = valid ? j : 0;
        float m = valid ? 1.0f : 0.0f;
#pragma unroll
        for (int k = 0; k < SENS; ++k) w1x[u][k] = m * W1[jj * 9 + k];
        wA[u] = m * W1[jj * 9 + 7]; wB[u] = m * W1[jj * 9 + 8];
        b1v[u] = m * b1[jj]; w20[u] = m * W2[jj]; w21[u] = m * W2[HID + jj];
    }
    const float b20 = b2[0], b21 = b2[1];
    const int addr_even = ((lane - 8) & 63) * 4;
    const int addr_odd  = ((lane + 8) & 63) * 4;
    const float* ci = comm_init + run * (NAG + 2);
    float prevV = ci[2 * g + 2];
    const float initV_e = ci[2 * g + 1];
    const float initV_o = ci[2 * g + 2];
    const float* pr = runs + (size_t)run * TSTEPS * NAG * SENS;
    float*       po = out  + (size_t)run * TSTEPS * NAG;
    auto xpart_pair = [&](const float2v (&r)[7], float (&ae)[3], float (&ao)[3]) {
#pragma unroll
        for (int u = 0; u < 3; ++u) {
            float e = b1v[u];
            e = fmaf(w1x[u][0], r[0].x, e); e = fmaf(w1x[u][1], r[0].y, e);
            e = fmaf(w1x[u][2], r[1].x, e); e = fmaf(w1x[u][3], r[1].y, e);
            e = fmaf(w1x[u][4], r[2].x, e); e = fmaf(w1x[u][5], r[2].y, e);
            e = fmaf(w1x[u][6], r[3].x, e);
            ae[u] = e;
            float o = b1v[u];
            o = fmaf(w1x[u][0], r[3].y, o); o = fmaf(w1x[u][1], r[4].x, o);
            o = fmaf(w1x[u][2], r[4].y, o); o = fmaf(w1x[u][3], r[5].x, o);
            o = fmaf(w1x[u][4], r[5].y, o); o = fmaf(w1x[u][5], r[6].x, o);
            o = fmaf(w1x[u][6], r[6].y, o);
            ao[u] = o;
        }
    };
    auto substep_even = [&](float x0, float x1, float x2, float& o0out) {
        float cross = bperm_fb(addr_even, prevV);
        float cL = g0 ? 0.f : cross;
        float a0 = fmaxf(fmaf(wA[0], cL, fmaf(wB[0], prevV, x0)), 0.f);
        float a1 = fmaxf(fmaf(wA[1], cL, fmaf(wB[1], prevV, x1)), 0.f);
        float a2 = fmaxf(fmaf(wA[2], cL, fmaf(wB[2], prevV, x2)), 0.f);
        float p0 = w20[0]*a0; p0 = fmaf(w20[1],a1,p0); p0 = fmaf(w20[2],a2,p0);
        float p1 = w21[0]*a0; p1 = fmaf(w21[1],a1,p1); p1 = fmaf(w21[2],a2,p1);
        o0out = grp_reduce_fb(p0) + b20;
        prevV = grp_reduce_fb(p1) + b21;
    };
    auto substep_odd = [&](float x0, float x1, float x2, float& o0out) {
        float cross = bperm_fb(addr_odd, prevV);
        float cR = g7 ? 0.f : cross;
        float a0 = fmaxf(fmaf(wB[0], cR, fmaf(wA[0], prevV, x0)), 0.f);
        float a1 = fmaxf(fmaf(wB[1], cR, fmaf(wA[1], prevV, x1)), 0.f);
        float a2 = fmaxf(fmaf(wB[2], cR, fmaf(wA[2], prevV, x2)), 0.f);
        float p0 = w20[0]*a0; p0 = fmaf(w20[1],a1,p0); p0 = fmaf(w20[2],a2,p0);
        float p1 = w21[0]*a0; p1 = fmaf(w21[1],a1,p1); p1 = fmaf(w21[2],a2,p1);
        o0out = grp_reduce_fb(p0) + b20;
        prevV = grp_reduce_fb(p1) + b21;
    };
    auto ramp_pair = [&](int s) {
        int t  = (s >> 1) - g;
        int tc = t < 0 ? 0 : (t > TSTEPS - 1 ? TSTEPS - 1 : t);
        const float2v* xp = (const float2v*)(pr + ((size_t)tc * NAG + 2 * g) * SENS);
        float2v r[7];
#pragma unroll
        for (int k = 0; k < 7; ++k) r[k] = xp[k];
        float ae[3], ao[3];
        xpart_pair(r, ae, ao);
        bool inr = (t >= 0) && (t < TSTEPS);
        float o0;
        substep_even(ae[0], ae[1], ae[2], o0);
        if (inr) po[(size_t)t * NAG + 2 * g] = o0;
        prevV = (t < 0) ? initV_e : prevV;
        substep_odd(ao[0], ao[1], ao[2], o0);
        if (inr) po[(size_t)t * NAG + 2 * g + 1] = o0;
        prevV = (t < 0) ? initV_o : prevV;
    };
#pragma unroll 1
    for (int s = 0; s <= 14; s += 2) ramp_pair(s);
    const float2v* xv = (const float2v*)(pr + ((size_t)(8 - g) * NAG + 2 * g) * SENS);
    float* oe = po + (size_t)(8 - g) * NAG + 2 * g;
    RawBlk RA, RB; XpBlk P0, P1;
    auto load_blk = [&](RawBlk& R, const float2v* p) {
#pragma unroll
        for (int j = 0; j < 4; ++j)
#pragma unroll
            for (int k = 0; k < 7; ++k) R.v[j][k] = p[j * 56 + k];
    };
    auto xpart_blk = [&](XpBlk& P, const RawBlk& R) {
#pragma unroll
        for (int j = 0; j < 4; ++j) xpart_pair(R.v[j], P.e[j], P.o[j]);
    };
    auto process_blk = [&](const XpBlk& P) {
#pragma unroll
        for (int j = 0; j < 4; ++j) {
            float o0;
            substep_even(P.e[j][0], P.e[j][1], P.e[j][2], o0); oe[0] = o0;
            substep_odd (P.o[j][0], P.o[j][1], P.o[j][2], o0); oe[1] = o0;
            oe += NAG;
        }
    };
    load_blk(RA, xv); load_blk(RB, xv + 224);
    xpart_blk(P0, RA); load_blk(RA, xv + 2 * 224);
#pragma unroll 1
    for (int bm = 0; bm < 506; bm += 2) {
        xpart_blk(P1, RB); load_blk(RB, xv + (size_t)(bm + 3) * 224);
        process_blk(P0);
        xpart_blk(P0, RA); load_blk(RA, xv + (size_t)(bm + 4) * 224);
        process_blk(P1);
    }
    xpart_blk(P1, RB); load_blk(RB, xv + (size_t)509 * 224);
    process_blk(P0);
    xpart_blk(P0, RA); process_blk(P1);
    xpart_blk(P1, RB); process_blk(P0); process_blk(P1);
#pragma unroll 1
    for (int s = 2 * TSTEPS; s <= 2 * TSTEPS + 12; s += 2) ramp_pair(s);
}

extern "C" void kernel_launch(void* const* d_in, const int* in_sizes, int n_in,
                              void* d_out, int out_size, void* d_ws, size_t ws_size,
                              hipStream_t stream) {
    const float* runs      = (const float*)d_in[0];
    const float* comm_init = (const float*)d_in[1];
    const float* W1        = (const float*)d_in[2];
    const float* b1        = (const float*)d_in[3];
    const float* W2        = (const float*)d_in[4];
    const float* b2        = (const float*)d_in[5];
    float* out = (float*)d_out;

    if (ws_size >= HPRE_BYTES) {
        char* hpre = (char*)d_ws;
        hipLaunchKernelGGL(hpre_kernel, dim3(4096), dim3(256), 0, stream,
                           runs, W1, b1, hpre);
        hipLaunchKernelGGL(comm_net_kernel, dim3(NRUNS), dim3(64), 0, stream,
                           (const unsigned int*)hpre, hpre, W1, W2, b2, comm_init);
        hipLaunchKernelGGL(finalize_kernel, dim3(16384), dim3(256), 0, stream,
                           (const char*)hpre, b2, out);
    } else {
        hipLaunchKernelGGL(comm_net_fb, dim3(NRUNS), dim3(64), 0, stream,
                           runs, comm_init, W1, b1, W2, b2, out);
    }
}